// Round 1
// baseline (142.430 us; speedup 1.0000x reference)
//
#include <hip/hip_runtime.h>
#include <hip/hip_bf16.h>
#include <math.h>

// TinyMoE: out = sum_e softmax(x@Wr)[e] * (gelu(x@w1[e]+b1[e]) @ w2[e] + b2[e])
// Restructured as two dense GEMMs: [32768x512]@[512x256] -> gelu/scale -> @[256x512(+b2 rows)]
// bf16 MFMA (16x16x32), fp32 router/softmax/gelu. 64 tokens per WG, 4 waves.

typedef short v8s __attribute__((ext_vector_type(8)));
typedef float v4f __attribute__((ext_vector_type(4)));

#define XS 520   // X LDS row stride (bf16 elems): 512 + 8 pad
#define HS 296   // H LDS row stride: 288 (=256 + 4 b2-weight rows + 28 zero pad) + 8 pad

__device__ __forceinline__ unsigned short f2bf(float f) {
    unsigned int u = __builtin_bit_cast(unsigned int, f);
    u += 0x7fffu + ((u >> 16) & 1u);
    return (unsigned short)(u >> 16);
}

// ---- prep: pack weights into bf16 MFMA B-fragment layout in workspace ----
// Block = 16(N) x 32(K) bf16, stored as [n_local*32 + k_local], 512 elems = 1KB.
// Lane l of a wave reads 16B at ((l&15)*32 + (l>>4)*8)*2 -> B[k][n], n=l&15, k=(l>>4)*8+j.
__global__ void moe_prep(const float* __restrict__ w1,   // (4,512,64)
                         const float* __restrict__ w2,   // (4,64,512)
                         const float* __restrict__ b2,   // (4,512)
                         const float* __restrict__ rw,   // (512,4)
                         unsigned short* __restrict__ w1p,
                         unsigned short* __restrict__ w2p,
                         unsigned short* __restrict__ rp) {
    int idx = blockIdx.x * 256 + threadIdx.x;
    if (idx < 131072) {
        // W1' [K=512][N=256], block = kb*16 + cb
        int block = idx >> 9, within = idx & 511;
        int kb = block >> 4, cb = block & 15;
        int n = within >> 5, kl = within & 31;
        int k = kb * 32 + kl;
        int col = cb * 16 + n;          // col in [0,256): e = col>>6, h = col&63
        int e = col >> 6, h = col & 63;
        w1p[idx] = f2bf(w1[(e * 512 + k) * 64 + h]);
    } else if (idx < 131072 + 147456) {
        // W2' [Kpad=288][N=512], block = kb*32 + cb. k in [256,260) = b2 rows, >=260 zero.
        int op = idx - 131072;
        int block = op >> 9, within = op & 511;
        int kb = block >> 5, cb = block & 31;
        int n = within >> 5, kl = within & 31;
        int k = kb * 32 + kl;
        int d = cb * 16 + n;
        float v = 0.f;
        if (k < 256) {
            int e = k >> 6, h = k & 63;
            v = w2[(e * 64 + h) * 512 + d];
        } else if (k < 260) {
            v = b2[(k - 256) * 512 + d];
        }
        w2p[op] = f2bf(v);
    } else if (idx < 131072 + 147456 + 8192) {
        // router W [K=512][N=16] (cols >=4 zero), block = kb
        int op = idx - (131072 + 147456);
        int kb = op >> 9, within = op & 511;
        int n = within >> 5, kl = within & 31;
        int k = kb * 32 + kl;
        float v = (n < 4) ? rw[k * 4 + n] : 0.f;
        rp[op] = f2bf(v);
    }
}

// ---- main fused kernel ----
__global__ __launch_bounds__(256, 2)
void moe_main(const float* __restrict__ x,
              const float* __restrict__ rb,
              const float* __restrict__ b1,
              const unsigned short* __restrict__ w1p,
              const unsigned short* __restrict__ w2p,
              const unsigned short* __restrict__ rp,
              float* __restrict__ out) {
    // X tile [64][XS] bf16 = 66560 B; H tile [64][HS] aliases it after GEMM1.
    __shared__ __align__(16) unsigned short lx[64 * XS];
    __shared__ float llog[64 * 4];
    __shared__ float lw[64 * 4];

    const int tid  = threadIdx.x;
    const int lane = tid & 63, wv = tid >> 6;
    const int lr = lane & 15, lq = lane >> 4;   // A: m=lr, k=lq*8+j ; B: n=lr ; C: col=lr, row=lq*4+r
    const long t0 = (long)blockIdx.x * 64;

    // ---- phase 0: stage X tile (fp32 global -> bf16 LDS) ----
    const float4* xt = (const float4*)(x + t0 * 512);
    #pragma unroll
    for (int it = 0; it < 32; ++it) {
        int F = it * 256 + tid;            // float4 index in 64x512 tile
        int row = F >> 7, c4 = F & 127;
        float4 v = xt[F];
        unsigned int p0 = (unsigned int)f2bf(v.x) | ((unsigned int)f2bf(v.y) << 16);
        unsigned int p1 = (unsigned int)f2bf(v.z) | ((unsigned int)f2bf(v.w) << 16);
        *(uint2*)&lx[row * XS + c4 * 4] = make_uint2(p0, p1);
    }
    __syncthreads();

    // ---- phase 1: router logits via MFMA (wave w -> tokens 16w..16w+15), softmax ----
    {
        v4f accR; accR[0] = accR[1] = accR[2] = accR[3] = 0.f;
        #pragma unroll
        for (int kb = 0; kb < 16; ++kb) {
            v8s a = *(const v8s*)(const void*)&lx[(16 * wv + lr) * XS + kb * 32 + lq * 8];
            v8s b = *(const v8s*)(const void*)&rp[kb * 512 + lr * 32 + lq * 8];
            accR = __builtin_amdgcn_mfma_f32_16x16x32_bf16(a, b, accR, 0, 0, 0);
        }
        if (lr < 4) {
            #pragma unroll
            for (int r = 0; r < 4; ++r)
                llog[(16 * wv + lq * 4 + r) * 4 + lr] = accR[r];
        }
    }
    __syncthreads();
    if (tid < 64) {
        float l[4];
        #pragma unroll
        for (int e = 0; e < 4; ++e) l[e] = llog[tid * 4 + e] + rb[e];
        float mx = fmaxf(fmaxf(l[0], l[1]), fmaxf(l[2], l[3]));
        float ex[4], s = 0.f;
        #pragma unroll
        for (int e = 0; e < 4; ++e) { ex[e] = expf(l[e] - mx); s += ex[e]; }
        float inv = 1.f / s;
        #pragma unroll
        for (int e = 0; e < 4; ++e) lw[tid * 4 + e] = ex[e] * inv;
    }
    __syncthreads();

    // ---- phase 2: GEMM1  C1[64][256] = X @ W1'; wave w owns cols [64w,64w+64) = expert w ----
    v4f acc1[4][4];
    #pragma unroll
    for (int mt = 0; mt < 4; ++mt)
        #pragma unroll
        for (int nt = 0; nt < 4; ++nt)
            acc1[mt][nt][0] = acc1[mt][nt][1] = acc1[mt][nt][2] = acc1[mt][nt][3] = 0.f;

    for (int kb = 0; kb < 16; ++kb) {
        v8s a[4], b[4];
        #pragma unroll
        for (int mt = 0; mt < 4; ++mt)
            a[mt] = *(const v8s*)(const void*)&lx[(16 * mt + lr) * XS + kb * 32 + lq * 8];
        #pragma unroll
        for (int nt = 0; nt < 4; ++nt)
            b[nt] = *(const v8s*)(const void*)&w1p[(size_t)(kb * 16 + wv * 4 + nt) * 512 + lr * 32 + lq * 8];
        #pragma unroll
        for (int mt = 0; mt < 4; ++mt)
            #pragma unroll
            for (int nt = 0; nt < 4; ++nt)
                acc1[mt][nt] = __builtin_amdgcn_mfma_f32_16x16x32_bf16(a[mt], b[nt], acc1[mt][nt], 0, 0, 0);
    }
    __syncthreads();   // all waves done reading X; lx may now be overwritten by H

    // epilogue: gelu(v+b1)*router_weight -> bf16 H[64][288] (cols 256..259 = router weights for b2 rows)
    {
        float b1v[4];
        #pragma unroll
        for (int nt = 0; nt < 4; ++nt) b1v[nt] = b1[wv * 64 + nt * 16 + lr];
        #pragma unroll
        for (int mt = 0; mt < 4; ++mt) {
            #pragma unroll
            for (int r = 0; r < 4; ++r) {
                int row = 16 * mt + lq * 4 + r;
                float wt = lw[row * 4 + wv];
                #pragma unroll
                for (int nt = 0; nt < 4; ++nt) {
                    float v = acc1[mt][nt][r] + b1v[nt];
                    float g = 0.5f * v * (1.f + erff(v * 0.70710678118f)) * wt;
                    lx[row * HS + wv * 64 + nt * 16 + lr] = f2bf(g);
                }
            }
        }
        // append router-weight cols (k=256..259) and zero pad (260..287)
        int r = tid >> 2, e = tid & 3;
        lx[r * HS + 256 + e] = f2bf(lw[tid]);
        #pragma unroll
        for (int i = 0; i < 7; ++i)
            lx[r * HS + 260 + e + 4 * i] = 0;
    }
    __syncthreads();

    // ---- phase 3: GEMM2  OUT[64][512] = H[64][288] @ W2'; wave w owns cols [128w,128w+128) ----
    v4f acc2[4][8];
    #pragma unroll
    for (int mt = 0; mt < 4; ++mt)
        #pragma unroll
        for (int nt = 0; nt < 8; ++nt)
            acc2[mt][nt][0] = acc2[mt][nt][1] = acc2[mt][nt][2] = acc2[mt][nt][3] = 0.f;

    for (int kb = 0; kb < 9; ++kb) {
        v8s a[4], b[8];
        #pragma unroll
        for (int mt = 0; mt < 4; ++mt)
            a[mt] = *(const v8s*)(const void*)&lx[(16 * mt + lr) * HS + kb * 32 + lq * 8];
        #pragma unroll
        for (int nt = 0; nt < 8; ++nt)
            b[nt] = *(const v8s*)(const void*)&w2p[(size_t)(kb * 32 + wv * 8 + nt) * 512 + lr * 32 + lq * 8];
        #pragma unroll
        for (int mt = 0; mt < 4; ++mt)
            #pragma unroll
            for (int nt = 0; nt < 8; ++nt)
                acc2[mt][nt] = __builtin_amdgcn_mfma_f32_16x16x32_bf16(a[mt], b[nt], acc2[mt][nt], 0, 0, 0);
    }

    float* ot = out + t0 * 512;
    #pragma unroll
    for (int mt = 0; mt < 4; ++mt)
        #pragma unroll
        for (int nt = 0; nt < 8; ++nt)
            #pragma unroll
            for (int r = 0; r < 4; ++r) {
                int row = 16 * mt + lq * 4 + r;
                int col = 128 * wv + 16 * nt + lr;
                ot[row * 512 + col] = acc2[mt][nt][r];
            }
}

extern "C" void kernel_launch(void* const* d_in, const int* in_sizes, int n_in,
                              void* d_out, int out_size, void* d_ws, size_t ws_size,
                              hipStream_t stream) {
    const float* x  = (const float*)d_in[0];
    const float* rw = (const float*)d_in[1];
    const float* rb = (const float*)d_in[2];
    const float* w1 = (const float*)d_in[3];
    const float* b1 = (const float*)d_in[4];
    const float* w2 = (const float*)d_in[5];
    const float* b2 = (const float*)d_in[6];

    unsigned short* w1p = (unsigned short*)d_ws;      // 131072 elems
    unsigned short* w2p = w1p + 131072;               // 147456 elems
    unsigned short* rp  = w2p + 147456;               // 8192 elems  (total ~573 KB)

    moe_prep<<<1120, 256, 0, stream>>>(w1, w2, b2, rw, w1p, w2p, rp);
    moe_main<<<512, 256, 0, stream>>>(x, rb, b1, w1p, w2p, rp, (float*)d_out);
}